// Round 5
// baseline (1181.037 us; speedup 1.0000x reference)
//
#include <hip/hip_runtime.h>
#include <hip/hip_bf16.h>
#include <cstdint>

// B=4, S=4096, E=2048, H=16, D=128 -> 16384 independent tokens.
// qkv = x @ W_qkv (16384x2048x6144); per-token 16x16 head mix;
// out = attn @ W_out + b_out (16384x2048x2048).

#define TOKENS 16384
#define EMB    2048
#define NQKV   6144

typedef __bf16 bf16x8_t __attribute__((ext_vector_type(8)));
typedef float  f32x4_t  __attribute__((ext_vector_type(4)));

#define GLOAD16(gsrc, ldst)                                                    \
  __builtin_amdgcn_global_load_lds(                                            \
      (const __attribute__((address_space(1))) void*)(uintptr_t)(gsrc),        \
      (__attribute__((address_space(3))) void*)(uint32_t)(uintptr_t)(ldst),    \
      16, 0, 0)

static __device__ __forceinline__ unsigned short f32_to_bf16_bits(float f) {
  union { float f; uint32_t u; } x; x.f = f;
  uint32_t u = x.u;
  u += 0x7fffu + ((u >> 16) & 1u);   // round-to-nearest-even
  return (unsigned short)(u >> 16);
}

// ---------------------------------------------------------------- converts
__global__ __launch_bounds__(256) void cvt_f32_bf16(
    const float4* __restrict__ in, ushort4* __restrict__ out, int n4) {
  const int stride = gridDim.x * blockDim.x;
  for (int i = blockIdx.x * blockDim.x + threadIdx.x; i < n4; i += stride) {
    float4 v = in[i];
    ushort4 o;
    o.x = f32_to_bf16_bits(v.x);
    o.y = f32_to_bf16_bits(v.y);
    o.z = f32_to_bf16_bits(v.z);
    o.w = f32_to_bf16_bits(v.w);
    out[i] = o;
  }
}

// transpose R x C f32 -> C x R bf16
__global__ __launch_bounds__(256) void transpose_cvt(
    const float* __restrict__ in, unsigned short* __restrict__ out, int R, int C) {
  __shared__ float tile[32][33];
  const int bx = blockIdx.x * 32;
  const int by = blockIdx.y * 32;
  const int tx = threadIdx.x;
  const int ty = threadIdx.y;
#pragma unroll
  for (int j = 0; j < 32; j += 8)
    tile[ty + j][tx] = in[(size_t)(by + ty + j) * C + bx + tx];
  __syncthreads();
#pragma unroll
  for (int j = 0; j < 32; j += 8)
    out[(size_t)(bx + ty + j) * R + by + tx] = f32_to_bf16_bits(tile[tx][ty + j]);
}

// ---------------------------------------------------------------- GEMM
// 256x256 tile, BK=64, 8 waves (2M x 4N), 4 phases/K-tile with DERIVED
// COUNTED WAITS: vmcnt(6) per phase (3 half-tiles in flight), counted
// lgkmcnt(12/8/8/12) (no full drain in steady state), every ds_read issued
// >=1 MFMA-phase before use. Quadrant order alternates per tile parity so
// 2A+2B register buffers suffice (register-neutral vs R2).
template <bool OUT_BF16>
__global__ __launch_bounds__(512, 1) void gemm_bt(
    const unsigned short* __restrict__ A,
    const unsigned short* __restrict__ BT,
    unsigned short* __restrict__ Cb,
    float* __restrict__ Cf,
    const float* __restrict__ bias,
    int M, int N) {
  constexpr int K = 2048;
  constexpr int BK = 64;
  constexpr int NKT = K / BK;          // 32
  __shared__ __align__(16) char lds[131072];  // [2 bufs][A 32KB | B 32KB]

  const int nbx = N / 256;
  const int nwg = gridDim.x;           // % 8 == 0
  const int bid = blockIdx.x;
  const int swzb = (bid & 7) * (nwg >> 3) + (bid >> 3);
  const int by = swzb / nbx;
  const int bx = swzb % nbx;

  const int t    = threadIdx.x;
  const int lane = t & 63;
  const int wid  = t >> 6;             // 0..7
  const int wr   = wid >> 2;           // 0..1 (M)
  const int wc   = wid & 3;            // 0..3 (N)
  const int lr   = lane & 15;
  const int g    = lane >> 4;          // 0..3

  const unsigned short* aSrc = A  + (size_t)by * 256 * K;
  const unsigned short* bSrc = BT + (size_t)bx * 256 * K;

  // staging source offsets (inverse-swizzled global, linear LDS dest)
  int aoff[2], boff[2];
#pragma unroll
  for (int i = 0; i < 2; ++i) {
    const int p   = (i * 512 + t) * 16;
    const int lo  = p ^ (((p >> 7) & 7) << 4);
    const int rih = lo >> 7;
    const int kbe = (lo & 127) >> 1;
    aoff[i] = (((rih >> 6) << 7) + (rih & 63)) * K + kbe;
    boff[i] = (((rih >> 5) << 6) + (rih & 31)) * K + kbe;
  }
  const int ldst = wid << 10;

  auto stageA = [&](int h, int k0, char* bufA) {
#pragma unroll
    for (int i = 0; i < 2; ++i)
      GLOAD16(aSrc + aoff[i] + h * (64 * K) + k0, bufA + h * 16384 + i * 8192 + ldst);
  };
  auto stageB = [&](int h, int k0, char* bufB) {
#pragma unroll
    for (int i = 0; i < 2; ++i)
      GLOAD16(bSrc + boff[i] + h * (32 * K) + k0, bufB + h * 16384 + i * 8192 + ldst);
  };

  // swizzled ds_read addresses
  const int sw   = (lr & 7) << 4;
  const int col0 = (g * 16) ^ sw;
  const int col1 = (64 + g * 16) ^ sw;
  const int aRow = (wr * 64 + lr) * 128;
  const int bRow = (wc * 32 + lr) * 128;

  f32x4_t acc[8][4] = {};
  bf16x8_t avA[4][2], avB[4][2];       // A quadrant frags [m2][ks]  (q0 / q1)
  bf16x8_t bvA[2][2], bvB[2][2];       // B pair frags [e][ks] (pair0 / pair1)

#define LDA_INTO(dst, bufA_, q)                                                \
  {                                                                            \
    const char* _b = (bufA_) + (q) * 16384 + aRow;                             \
    _Pragma("unroll") for (int m2 = 0; m2 < 4; ++m2) {                         \
      dst[m2][0] = *(const bf16x8_t*)(_b + m2 * 2048 + col0);                  \
      dst[m2][1] = *(const bf16x8_t*)(_b + m2 * 2048 + col1);                  \
    }                                                                          \
  }
#define LDB_INTO(dst, bufB_, pair)                                             \
  {                                                                            \
    _Pragma("unroll") for (int e = 0; e < 2; ++e) {                            \
      const int nf = (pair) * 2 + e;                                           \
      const char* _b = (bufB_) + (nf >> 1) * 16384 + (nf & 1) * 2048 + bRow;   \
      dst[e][0] = *(const bf16x8_t*)(_b + col0);                               \
      dst[e][1] = *(const bf16x8_t*)(_b + col1);                               \
    }                                                                          \
  }
#define MFMAQ(AV, BV, Q, PAIR)                                                 \
  _Pragma("unroll") for (int m2 = 0; m2 < 4; ++m2)                             \
  _Pragma("unroll") for (int e = 0; e < 2; ++e)                                \
  _Pragma("unroll") for (int ks = 0; ks < 2; ++ks)                             \
    acc[(Q) * 4 + m2][(PAIR) * 2 + e] = __builtin_amdgcn_mfma_f32_16x16x32_bf16( \
        AV[m2][ks], BV[ks == 0 ? (e) : (e)][ks], acc[(Q) * 4 + m2][(PAIR) * 2 + e], 0, 0, 0);

#define SBR __builtin_amdgcn_sched_barrier(0)
#define BAR __builtin_amdgcn_s_barrier()
#define VMW(S2C)                                                               \
  { if (S2C) { asm volatile("s_waitcnt vmcnt(6)" ::: "memory"); }              \
    else     { asm volatile("s_waitcnt vmcnt(0)" ::: "memory"); } }            \
  SBR;
#define LG(NN) { asm volatile("s_waitcnt lgkmcnt(" #NN ")" ::: "memory"); } SBR;
#define PRIO1 __builtin_amdgcn_s_setprio(1);
#define PRIO0 __builtin_amdgcn_s_setprio(0); SBR;

  // One K-tile, 4 phases. BVF/PF = first-used B reg/pair; BVS/PS = second.
  // Parity alternates: even (bvA,0 | bvB,1); odd (bvB,1 | bvA,0).
#define BODY(KT, S1, S2, CA, CB, NA, NB, BVF, BVS, PF, PS)                     \
  {                                                                            \
    const int k1 = ((KT) + 1) * BK, k2 = ((KT) + 2) * BK;                      \
    /* P1: reads BVS<-pairS(cur), avB<-q1(cur); stage BhS(kt+1) */             \
    VMW(S2);                                                                   \
    LDB_INTO(BVS, CB, PS); SBR;                                                \
    LDA_INTO(avB, CA, 1); SBR;                                                 \
    if (S1) { stageB(PF, k1, NB); } SBR;                                       \
    BAR; LG(12); PRIO1; MFMAQ(avA, BVF, 0, PF); PRIO0; BAR;                    \
    /* P2: stage Ah0(kt+2) */                                                  \
    VMW(S2);                                                                   \
    if (S2) { stageA(0, k2, CA); } SBR;                                        \
    BAR; LG(8); PRIO1; MFMAQ(avA, BVS, 0, PS); PRIO0; BAR;                     \
    /* P3: read avA<-q0(next); stage BhF(kt+2) */                              \
    VMW(S2);                                                                   \
    if (S1) { LDA_INTO(avA, NA, 0); } SBR;                                     \
    if (S2) { stageB(PF, k2, CB); } SBR;                                       \
    BAR;                                                                       \
    if (S1) { LG(8); } else { LG(0); }                                         \
    PRIO1; MFMAQ(avB, BVS, 1, PS); PRIO0; BAR;                                 \
    /* P4: read BVS<-pairF(next); stage Ah1(kt+2) */                           \
    VMW(S2);                                                                   \
    if (S1) { LDB_INTO(BVS, NB, PS); } SBR;                                    \
    if (S2) { stageA(1, k2, CA); } SBR;                                        \
    BAR;                                                                       \
    if (S1) { LG(12); } else { LG(0); }                                        \
    PRIO1; MFMAQ(avB, BVF, 1, PF); PRIO0; BAR;                                 \
  }

  char* b0A = lds;
  char* b0B = lds + 32768;
  char* b1A = lds + 65536;
  char* b1B = b1A + 32768;

  // prologue: tile0 full; tile1 {Ah0, BhF(odd)=h1, Ah1}; pre-read avA,bvA(tile0)
  stageA(0, 0, b0A); stageA(1, 0, b0A);
  stageB(0, 0, b0B); stageB(1, 0, b0B);
  stageA(0, BK, b1A);
  stageB(1, BK, b1B);
  stageA(1, BK, b1A);
  asm volatile("s_waitcnt vmcnt(6)" ::: "memory");  // tile0 landed
  BAR;
  LDA_INTO(avA, b0A, 0);
  LDB_INTO(bvA, b0B, 0);
  SBR;

  // steady: tiles 0..NKT-3 (full pipeline), peel last two
  for (int kt = 0; kt < NKT - 2; kt += 2) {
    BODY(kt,     1, 1, b0A, b0B, b1A, b1B, bvA, bvB, 0, 1);
    BODY(kt + 1, 1, 1, b1A, b1B, b0A, b0B, bvB, bvA, 1, 0);
  }
  BODY(NKT - 2, 1, 0, b0A, b0B, b1A, b1B, bvA, bvB, 0, 1);
  BODY(NKT - 1, 0, 0, b1A, b1B, b0A, b0B, bvB, bvA, 1, 0);

  // epilogue: C/D map col=lane&15, row=(lane>>4)*4+j
  const int rbase = by * 256 + wr * 128 + g * 4;
  const int cbase = bx * 256 + wc * 64 + lr;
#pragma unroll
  for (int m = 0; m < 8; ++m) {
#pragma unroll
    for (int nf = 0; nf < 4; ++nf) {
      const int col = cbase + nf * 16;
#pragma unroll
      for (int j = 0; j < 4; ++j) {
        const size_t off = (size_t)(rbase + (m >> 2) * 64 + (m & 3) * 16 + j) * N + col;
        if constexpr (OUT_BF16) {
          Cb[off] = f32_to_bf16_bits(acc[m][nf][j]);
        } else {
          Cf[off] = acc[m][nf][j] + bias[col];
        }
      }
    }
  }
#undef LDA_INTO
#undef LDB_INTO
#undef MFMAQ
#undef SBR
#undef BAR
#undef VMW
#undef LG
#undef PRIO1
#undef PRIO0
#undef BODY
}

// ---------------------------------------------------------------- attention
__global__ __launch_bounds__(256) void attn_heads(
    const unsigned short* __restrict__ qkv,  // [T][6144] bf16
    unsigned short* __restrict__ attn) {     // [T][2048] bf16
  __shared__ __align__(16) unsigned short sQKV[NQKV];
  __shared__ float sW[16][16];

  const int t = threadIdx.x;
  const size_t qbase = (size_t)blockIdx.x * NQKV;

  const uint4* gp = (const uint4*)(qkv + qbase);
  uint4* l = (uint4*)sQKV;
#pragma unroll
  for (int i = 0; i < 3; ++i) {
    const int idx = i * 256 + t;
    int dst = idx;
    if (idx >= 256 && idx < 512) {
      const int r = (idx - 256) >> 4;
      const int c = idx & 15;
      dst = 256 + r * 16 + (c ^ (r & 7));
    }
    l[dst] = gp[idx];
  }
  __syncthreads();

  const int h = t >> 4;
  const int H = t & 15;
  const bf16x8_t* q8 = (const bf16x8_t*)sQKV + h * 16;
  const bf16x8_t* k8 = (const bf16x8_t*)sQKV + 256;
  float s = 0.f;
#pragma unroll
  for (int d8 = 0; d8 < 16; ++d8) {
    bf16x8_t qv = q8[d8];
    bf16x8_t kv = k8[H * 16 + (d8 ^ (H & 7))];
#pragma unroll
    for (int j = 0; j < 8; ++j)
      s = fmaf((float)qv[j], (float)kv[j], s);
  }
  s *= 0.08838834764831843f;

  float mx = s;
#pragma unroll
  for (int o = 8; o; o >>= 1) mx = fmaxf(mx, __shfl_xor(mx, o));
  const float e = __expf(s - mx);
  float sum = e;
#pragma unroll
  for (int o = 8; o; o >>= 1) sum += __shfl_xor(sum, o);
  sW[h][H] = e / sum;
  __syncthreads();

  const int d0c = t & 15;
  const bf16x8_t* v8 = (const bf16x8_t*)sQKV + 512;
  float accv[8] = {};
#pragma unroll
  for (int j = 0; j < 16; ++j) {
    const float w = sW[h][j];
    const bf16x8_t vv = v8[j * 16 + d0c];
#pragma unroll
    for (int jj = 0; jj < 8; ++jj)
      accv[jj] = fmaf(w, (float)vv[jj], accv[jj]);
  }
  bf16x8_t o;
#pragma unroll
  for (int jj = 0; jj < 8; ++jj) o[jj] = (__bf16)accv[jj];
  *(bf16x8_t*)(attn + (size_t)blockIdx.x * EMB + h * 128 + d0c * 8) = o;
}

// ---------------------------------------------------------------- launch
extern "C" void kernel_launch(void* const* d_in, const int* in_sizes, int n_in,
                              void* d_out, int out_size, void* d_ws, size_t ws_size,
                              hipStream_t stream) {
  const float* x    = (const float*)d_in[0];
  const float* Wqkv = (const float*)d_in[1];
  const float* Wout = (const float*)d_in[2];
  const float* bout = (const float*)d_in[3];
  float* out = (float*)d_out;

  unsigned short* xb    = (unsigned short*)d_ws;          // 33,554,432
  unsigned short* wqkvT = xb    + (size_t)33554432;       // 12,582,912
  unsigned short* woutT = wqkvT + (size_t)12582912;       //  4,194,304
  unsigned short* qkv   = woutT + (size_t)4194304;        // 100,663,296
  unsigned short* attn  = qkv   + (size_t)100663296;      // 33,554,432

  cvt_f32_bf16<<<2048, 256, 0, stream>>>((const float4*)x, (ushort4*)xb, 33554432 / 4);
  transpose_cvt<<<dim3(6144 / 32, 2048 / 32), dim3(32, 8), 0, stream>>>(Wqkv, wqkvT, 2048, 6144);
  transpose_cvt<<<dim3(2048 / 32, 2048 / 32), dim3(32, 8), 0, stream>>>(Wout, woutT, 2048, 2048);
  // qkv = x @ W_qkv : grid 64*24 = 1536 (%8==0)
  gemm_bt<true><<<(16384 / 256) * (6144 / 256), 512, 0, stream>>>(
      xb, wqkvT, qkv, nullptr, nullptr, 16384, 6144);
  attn_heads<<<TOKENS, 256, 0, stream>>>(qkv, attn);
  // out = attn @ W_out + b_out : grid 64*8 = 512 (%8==0)
  gemm_bt<false><<<(16384 / 256) * (2048 / 256), 512, 0, stream>>>(
      attn, woutT, nullptr, out, bout, 16384, 2048);
}

// Round 6
// 670.423 us; speedup vs baseline: 1.7616x; 1.7616x over previous
//
#include <hip/hip_runtime.h>
#include <hip/hip_bf16.h>
#include <cstdint>

// B=4, S=4096, E=2048, H=16, D=128 -> 16384 independent tokens.
// qkv = x @ W_qkv (16384x2048x6144); per-token 16x16 head mix;
// out = attn @ W_out + b_out (16384x2048x2048).

#define TOKENS 16384
#define EMB    2048
#define NQKV   6144

typedef __bf16 bf16x8_t __attribute__((ext_vector_type(8)));
typedef float  f32x4_t  __attribute__((ext_vector_type(4)));

#define GLOAD16(gsrc, ldst)                                                    \
  __builtin_amdgcn_global_load_lds(                                            \
      (const __attribute__((address_space(1))) void*)(uintptr_t)(gsrc),        \
      (__attribute__((address_space(3))) void*)(uint32_t)(uintptr_t)(ldst),    \
      16, 0, 0)

static __device__ __forceinline__ unsigned short f32_to_bf16_bits(float f) {
  union { float f; uint32_t u; } x; x.f = f;
  uint32_t u = x.u;
  u += 0x7fffu + ((u >> 16) & 1u);   // round-to-nearest-even
  return (unsigned short)(u >> 16);
}

// ---------------------------------------------------------------- converts
__global__ __launch_bounds__(256) void cvt_f32_bf16(
    const float4* __restrict__ in, ushort4* __restrict__ out, int n4) {
  const int stride = gridDim.x * blockDim.x;
  for (int i = blockIdx.x * blockDim.x + threadIdx.x; i < n4; i += stride) {
    float4 v = in[i];
    ushort4 o;
    o.x = f32_to_bf16_bits(v.x);
    o.y = f32_to_bf16_bits(v.y);
    o.z = f32_to_bf16_bits(v.z);
    o.w = f32_to_bf16_bits(v.w);
    out[i] = o;
  }
}

// transpose R x C f32 -> C x R bf16
__global__ __launch_bounds__(256) void transpose_cvt(
    const float* __restrict__ in, unsigned short* __restrict__ out, int R, int C) {
  __shared__ float tile[32][33];
  const int bx = blockIdx.x * 32;
  const int by = blockIdx.y * 32;
  const int tx = threadIdx.x;
  const int ty = threadIdx.y;
#pragma unroll
  for (int j = 0; j < 32; j += 8)
    tile[ty + j][tx] = in[(size_t)(by + ty + j) * C + bx + tx];
  __syncthreads();
#pragma unroll
  for (int j = 0; j < 32; j += 8)
    out[(size_t)(bx + ty + j) * R + by + tx] = f32_to_bf16_bits(tile[tx][ty + j]);
}

// ---------------------------------------------------------------- GEMM
// PERSISTENT 256x256-tile GEMM: grid = 256 blocks (1/CU), each block
// processes ROUNDS output tiles with the K-pipeline running continuously
// across tiles (last 2 K-tiles of round r stage round r+1's first K-tiles).
// Inner schedule identical to the verified R4 kernel (4 phases/K-tile,
// av0-next prefetch at P4 with lgkmcnt(8) tolerance, vmcnt(4)/K-tile).
template <bool OUT_BF16, int ROUNDS, int NBX>
__global__ __launch_bounds__(512, 1) void gemm_bt(
    const unsigned short* __restrict__ A,
    const unsigned short* __restrict__ BT,
    unsigned short* __restrict__ Cb,
    float* __restrict__ Cf,
    const float* __restrict__ bias) {
  constexpr int K = 2048;
  constexpr int BK = 64;
  constexpr int NKT = K / BK;          // 32
  constexpr int N = NBX * 256;
  __shared__ __align__(16) char lds[131072];  // [2 bufs][A 32KB | B 32KB]

  const int bid = blockIdx.x;
  // XCD-chunked persistent tiling: XCD x owns tiles [x*32*ROUNDS, ...);
  // its 32 blocks walk the chunk 32 tiles per round (same locality as the
  // previous per-tile swizzle).
  const int chunk = (bid & 7) * (32 * ROUNDS) + (bid >> 3);

  const int t    = threadIdx.x;
  const int lane = t & 63;
  const int wid  = t >> 6;             // 0..7
  const int wr   = wid >> 2;           // 0..1 (M)
  const int wc   = wid & 3;            // 0..3 (N)
  const int lr   = lane & 15;
  const int g    = lane >> 4;          // 0..3

  // staging source offsets (inverse-swizzled global, linear LDS dest)
  int aoff[2], boff[2];
#pragma unroll
  for (int i = 0; i < 2; ++i) {
    const int p   = (i * 512 + t) * 16;
    const int lo  = p ^ (((p >> 7) & 7) << 4);
    const int rih = lo >> 7;
    const int kbe = (lo & 127) >> 1;
    aoff[i] = (((rih >> 6) << 7) + (rih & 63)) * K + kbe;
    boff[i] = (((rih >> 5) << 6) + (rih & 31)) * K + kbe;
  }
  const int ldst = wid << 10;

  auto stageA = [&](const unsigned short* src, int h, int k0, char* bufA) {
#pragma unroll
    for (int i = 0; i < 2; ++i)
      GLOAD16(src + aoff[i] + h * (64 * K) + k0, bufA + h * 16384 + i * 8192 + ldst);
  };
  auto stageB = [&](const unsigned short* src, int h, int k0, char* bufB) {
#pragma unroll
    for (int i = 0; i < 2; ++i)
      GLOAD16(src + boff[i] + h * (32 * K) + k0, bufB + h * 16384 + i * 8192 + ldst);
  };

  // swizzled ds_read addresses
  const int sw   = (lr & 7) << 4;
  const int col0 = (g * 16) ^ sw;
  const int col1 = (64 + g * 16) ^ sw;
  const int aRow = (wr * 64 + lr) * 128;
  const int bRow = (wc * 32 + lr) * 128;

  f32x4_t acc[8][4] = {};
  bf16x8_t av0[4][2], av1[4][2];       // A quadrant frags [m2][ks]
  bf16x8_t bv0[2][2], bv1[2][2];       // B pair frags [e][ks]

#define LDA_INTO(dst, bufA_, q)                                                \
  {                                                                            \
    const char* _b = (bufA_) + (q) * 16384 + aRow;                             \
    _Pragma("unroll") for (int m2 = 0; m2 < 4; ++m2) {                         \
      dst[m2][0] = *(const bf16x8_t*)(_b + m2 * 2048 + col0);                  \
      dst[m2][1] = *(const bf16x8_t*)(_b + m2 * 2048 + col1);                  \
    }                                                                          \
  }
#define LDB_INTO(dst, bufB_, pair)                                             \
  {                                                                            \
    _Pragma("unroll") for (int e = 0; e < 2; ++e) {                            \
      const int nf = (pair) * 2 + e;                                           \
      const char* _b = (bufB_) + (nf >> 1) * 16384 + (nf & 1) * 2048 + bRow;   \
      dst[e][0] = *(const bf16x8_t*)(_b + col0);                               \
      dst[e][1] = *(const bf16x8_t*)(_b + col1);                               \
    }                                                                          \
  }
#define MFMAQ(AV, BV, Q, PAIR)                                                 \
  _Pragma("unroll") for (int m2 = 0; m2 < 4; ++m2)                             \
  _Pragma("unroll") for (int e = 0; e < 2; ++e)                                \
  _Pragma("unroll") for (int ks = 0; ks < 2; ++ks)                             \
    acc[(Q) * 4 + m2][(PAIR) * 2 + e] = __builtin_amdgcn_mfma_f32_16x16x32_bf16( \
        AV[m2][ks], BV[e][ks], acc[(Q) * 4 + m2][(PAIR) * 2 + e], 0, 0, 0);

#define SBR __builtin_amdgcn_sched_barrier(0)
#define TAIL(NN)                                                               \
  SBR; __builtin_amdgcn_s_barrier();                                           \
  asm volatile("s_waitcnt lgkmcnt(" #NN ")" ::: "memory");                     \
  SBR; __builtin_amdgcn_s_setprio(1);
#define PEND                                                                   \
  __builtin_amdgcn_s_setprio(0); SBR; __builtin_amdgcn_s_barrier();

  // ---- round-0 panels + prologue: tile0 full + tile1 {Ah0, Bh1}
  int tid = chunk;
  int by = tid / NBX;
  int bx = tid % NBX;
  const unsigned short* aC = A  + (size_t)by * 256 * K;
  const unsigned short* bC = BT + (size_t)bx * 256 * K;
  {
    char* b0A = lds;
    char* b0B = lds + 32768;
    char* b1A = lds + 65536;
    char* b1B = b1A + 32768;
    stageA(aC, 0, 0, b0A); stageA(aC, 1, 0, b0A);
    stageB(bC, 0, 0, b0B); stageB(bC, 1, 0, b0B);
    stageA(aC, 0, BK, b1A);
    stageB(bC, 1, BK, b1B);
    asm volatile("s_waitcnt vmcnt(4)" ::: "memory");  // tile0 landed
    __builtin_amdgcn_s_barrier();
    LDA_INTO(av0, b0A, 0);
  }

  for (int r = 0; r < ROUNDS; ++r) {
    const bool lastR = (r == ROUNDS - 1);
    const int tidn = chunk + 32 * (lastR ? r : r + 1);
    const int byn = tidn / NBX;
    const int bxn = tidn % NBX;
    const unsigned short* aN = A  + (size_t)byn * 256 * K;
    const unsigned short* bN = BT + (size_t)bxn * 256 * K;

    for (int kt = 0; kt < NKT; ++kt) {
      char* cA = lds + (kt & 1) * 65536;
      char* cB = cA + 32768;
      char* nA = lds + ((kt + 1) & 1) * 65536;
      char* nB = nA + 32768;
      const bool w1 = (kt + 1 >= NKT);   // kt+1 wraps to next round
      const bool w2 = (kt + 2 >= NKT);   // kt+2 wraps to next round
      const bool s1 = !w1 || !lastR;
      const bool s2 = !w2 || !lastR;
      const unsigned short* A1 = w1 ? aN : aC;
      const unsigned short* B1 = w1 ? bN : bC;
      const unsigned short* A2 = w2 ? aN : aC;
      const unsigned short* B2 = w2 ? bN : bC;
      const int k1 = w1 ? 0 : (kt + 1) * BK;
      const int k2 = w2 ? (kt + 2 - NKT) * BK : (kt + 2) * BK;

      // P1: read bv0(cur); stage (kt+1)Ah1 -> nA; M1 = (q0, p0)
      LDB_INTO(bv0, cB, 0);
      if (s1) stageA(A1, 1, k1, nA);
      TAIL(0); MFMAQ(av0, bv0, 0, 0); PEND;

      // P2: read bv1(cur) then av1(cur); stage (kt+1)Bh0 -> nB; M2 = (q0, p1)
      LDB_INTO(bv1, cB, 1);
      LDA_INTO(av1, cA, 1);
      if (s1) stageB(B1, 0, k1, nB);
      TAIL(8); MFMAQ(av0, bv1, 0, 1); PEND;   // drains exactly bv1 (FIFO)

      // P3: stage (kt+2)Ah0 -> cA; M3 = (q1, p1)
      if (s2) stageA(A2, 0, k2, cA);
      TAIL(0); MFMAQ(av1, bv1, 1, 1); PEND;

      // P4: stage (kt+2)Bh1 -> cB; counted vmcnt; prefetch next av0; M4 = (q1, p0)
      if (s2) stageB(B2, 1, k2, cB);
      if (s2) { asm volatile("s_waitcnt vmcnt(4)" ::: "memory"); }
      else    { asm volatile("s_waitcnt vmcnt(0)" ::: "memory"); }
      if (s1) {
        LDA_INTO(av0, nA, 0);   // next K-tile's q0 (possibly next round's tile0)
        TAIL(8);
      } else {
        TAIL(0);
      }
      MFMAQ(av1, bv0, 1, 0); PEND;
    }

    // ---- per-round epilogue: store acc for (by,bx), zero acc.
    // C/D map: col=lane&15, row=(lane>>4)*4+j
    {
      const int rbase = by * 256 + wr * 128 + g * 4;
      const int cbase = bx * 256 + wc * 64 + lr;
#pragma unroll
      for (int m = 0; m < 8; ++m) {
#pragma unroll
        for (int nf = 0; nf < 4; ++nf) {
          const int col = cbase + nf * 16;
#pragma unroll
          for (int j = 0; j < 4; ++j) {
            const size_t off = (size_t)(rbase + (m >> 2) * 64 + (m & 3) * 16 + j) * N + col;
            if constexpr (OUT_BF16) {
              Cb[off] = f32_to_bf16_bits(acc[m][nf][j]);
            } else {
              Cf[off] = acc[m][nf][j] + bias[col];
            }
            acc[m][nf][j] = 0.0f;
          }
        }
      }
    }
    by = byn; bx = bxn; aC = aN; bC = bN;
  }
#undef LDA_INTO
#undef LDB_INTO
#undef MFMAQ
#undef SBR
#undef TAIL
#undef PEND
}

// ---------------------------------------------------------------- attention
__global__ __launch_bounds__(256) void attn_heads(
    const unsigned short* __restrict__ qkv,  // [T][6144] bf16
    unsigned short* __restrict__ attn) {     // [T][2048] bf16
  __shared__ __align__(16) unsigned short sQKV[NQKV];
  __shared__ float sW[16][16];

  const int t = threadIdx.x;
  const size_t qbase = (size_t)blockIdx.x * NQKV;

  const uint4* gp = (const uint4*)(qkv + qbase);
  uint4* l = (uint4*)sQKV;
#pragma unroll
  for (int i = 0; i < 3; ++i) {
    const int idx = i * 256 + t;
    int dst = idx;
    if (idx >= 256 && idx < 512) {
      const int r = (idx - 256) >> 4;
      const int c = idx & 15;
      dst = 256 + r * 16 + (c ^ (r & 7));
    }
    l[dst] = gp[idx];
  }
  __syncthreads();

  const int h = t >> 4;
  const int H = t & 15;
  const bf16x8_t* q8 = (const bf16x8_t*)sQKV + h * 16;
  const bf16x8_t* k8 = (const bf16x8_t*)sQKV + 256;
  float s = 0.f;
#pragma unroll
  for (int d8 = 0; d8 < 16; ++d8) {
    bf16x8_t qv = q8[d8];
    bf16x8_t kv = k8[H * 16 + (d8 ^ (H & 7))];
#pragma unroll
    for (int j = 0; j < 8; ++j)
      s = fmaf((float)qv[j], (float)kv[j], s);
  }
  s *= 0.08838834764831843f;

  float mx = s;
#pragma unroll
  for (int o = 8; o; o >>= 1) mx = fmaxf(mx, __shfl_xor(mx, o));
  const float e = __expf(s - mx);
  float sum = e;
#pragma unroll
  for (int o = 8; o; o >>= 1) sum += __shfl_xor(sum, o);
  sW[h][H] = e / sum;
  __syncthreads();

  const int d0c = t & 15;
  const bf16x8_t* v8 = (const bf16x8_t*)sQKV + 512;
  float accv[8] = {};
#pragma unroll
  for (int j = 0; j < 16; ++j) {
    const float w = sW[h][j];
    const bf16x8_t vv = v8[j * 16 + d0c];
#pragma unroll
    for (int jj = 0; jj < 8; ++jj)
      accv[jj] = fmaf(w, (float)vv[jj], accv[jj]);
  }
  bf16x8_t o;
#pragma unroll
  for (int jj = 0; jj < 8; ++jj) o[jj] = (__bf16)accv[jj];
  *(bf16x8_t*)(attn + (size_t)blockIdx.x * EMB + h * 128 + d0c * 8) = o;
}

// ---------------------------------------------------------------- launch
extern "C" void kernel_launch(void* const* d_in, const int* in_sizes, int n_in,
                              void* d_out, int out_size, void* d_ws, size_t ws_size,
                              hipStream_t stream) {
  const float* x    = (const float*)d_in[0];
  const float* Wqkv = (const float*)d_in[1];
  const float* Wout = (const float*)d_in[2];
  const float* bout = (const float*)d_in[3];
  float* out = (float*)d_out;

  unsigned short* xb    = (unsigned short*)d_ws;          // 33,554,432
  unsigned short* wqkvT = xb    + (size_t)33554432;       // 12,582,912
  unsigned short* woutT = wqkvT + (size_t)12582912;       //  4,194,304
  unsigned short* qkv   = woutT + (size_t)4194304;        // 100,663,296
  unsigned short* attn  = qkv   + (size_t)100663296;      // 33,554,432

  cvt_f32_bf16<<<2048, 256, 0, stream>>>((const float4*)x, (ushort4*)xb, 33554432 / 4);
  transpose_cvt<<<dim3(6144 / 32, 2048 / 32), dim3(32, 8), 0, stream>>>(Wqkv, wqkvT, 2048, 6144);
  transpose_cvt<<<dim3(2048 / 32, 2048 / 32), dim3(32, 8), 0, stream>>>(Wout, woutT, 2048, 2048);
  // qkv = x @ W_qkv : persistent, 256 blocks x 6 rounds = 1536 tiles
  gemm_bt<true, 6, 24><<<256, 512, 0, stream>>>(
      xb, wqkvT, qkv, nullptr, nullptr);
  attn_heads<<<TOKENS, 256, 0, stream>>>(qkv, attn);
  // out = attn @ W_out + b_out : persistent, 256 blocks x 2 rounds = 512 tiles
  gemm_bt<false, 2, 8><<<256, 512, 0, stream>>>(
      attn, woutT, nullptr, out, bout);
}

// Round 8
// 643.983 us; speedup vs baseline: 1.8340x; 1.0411x over previous
//
#include <hip/hip_runtime.h>
#include <hip/hip_bf16.h>
#include <cstdint>

// B=4, S=4096, E=2048, H=16, D=128 -> 16384 independent tokens.
// qkv = x @ W_qkv (16384x2048x6144); per-token 16x16 head mix;
// out = attn @ W_out + b_out (16384x2048x2048).

#define TOKENS 16384
#define EMB    2048
#define NQKV   6144

typedef __bf16 bf16x8_t __attribute__((ext_vector_type(8)));
typedef float  f32x4_t  __attribute__((ext_vector_type(4)));

#define GLOAD16(gsrc, ldst)                                                    \
  __builtin_amdgcn_global_load_lds(                                            \
      (const __attribute__((address_space(1))) void*)(uintptr_t)(gsrc),        \
      (__attribute__((address_space(3))) void*)(uint32_t)(uintptr_t)(ldst),    \
      16, 0, 0)

static __device__ __forceinline__ unsigned short f32_to_bf16_bits(float f) {
  union { float f; uint32_t u; } x; x.f = f;
  uint32_t u = x.u;
  u += 0x7fffu + ((u >> 16) & 1u);   // round-to-nearest-even
  return (unsigned short)(u >> 16);
}

// ---------------------------------------------------------------- converts
__global__ __launch_bounds__(256) void cvt_f32_bf16(
    const float4* __restrict__ in, ushort4* __restrict__ out, int n4) {
  const int stride = gridDim.x * blockDim.x;
  for (int i = blockIdx.x * blockDim.x + threadIdx.x; i < n4; i += stride) {
    float4 v = in[i];
    ushort4 o;
    o.x = f32_to_bf16_bits(v.x);
    o.y = f32_to_bf16_bits(v.y);
    o.z = f32_to_bf16_bits(v.z);
    o.w = f32_to_bf16_bits(v.w);
    out[i] = o;
  }
}

// transpose R x C f32 -> C x R bf16
__global__ __launch_bounds__(256) void transpose_cvt(
    const float* __restrict__ in, unsigned short* __restrict__ out, int R, int C) {
  __shared__ float tile[32][33];
  const int bx = blockIdx.x * 32;
  const int by = blockIdx.y * 32;
  const int tx = threadIdx.x;
  const int ty = threadIdx.y;
#pragma unroll
  for (int j = 0; j < 32; j += 8)
    tile[ty + j][tx] = in[(size_t)(by + ty + j) * C + bx + tx];
  __syncthreads();
#pragma unroll
  for (int j = 0; j < 32; j += 8)
    out[(size_t)(bx + ty + j) * R + by + tx] = f32_to_bf16_bits(tile[tx][ty + j]);
}

// ---------------------------------------------------------------- GEMM
// 256x256 tile, BK=64, 8 waves (2M x 4N), 4 phases/K-tile.
// R4 schedule + post-MFMA B-read skew. Cross-wave DMA safety rule: a ds_read
// of DMA-staged data must follow (all waves' draining vmcnt) -> s_barrier.
//   bv1 read post-M1 (data covered by P4(kt-1) vmcnt+barrier),
//   bv0n read post-M4 (covered by THIS P4's vmcnt(4)+TAIL barrier).
// Counted lgkm: P1 TAIL(0) [drain av0n+bv0n], P2 TAIL(8) [drain bv1, keep
// av1], P3 TAIL(0) [drain av1], P4 TAIL(8) [keep av0n]. Registers == R4.
template <bool OUT_BF16>
__global__ __launch_bounds__(512, 1) void gemm_bt(
    const unsigned short* __restrict__ A,
    const unsigned short* __restrict__ BT,
    unsigned short* __restrict__ Cb,
    float* __restrict__ Cf,
    const float* __restrict__ bias,
    int M, int N) {
  constexpr int K = 2048;
  constexpr int BK = 64;
  constexpr int NKT = K / BK;          // 32
  __shared__ __align__(16) char lds[131072];  // [2 bufs][A 32KB | B 32KB]

  const int nbx = N / 256;
  const int nwg = gridDim.x;           // % 8 == 0
  const int bid = blockIdx.x;
  const int swzb = (bid & 7) * (nwg >> 3) + (bid >> 3);
  const int by = swzb / nbx;
  const int bx = swzb % nbx;

  const int t    = threadIdx.x;
  const int lane = t & 63;
  const int wid  = t >> 6;             // 0..7
  const int wr   = wid >> 2;           // 0..1 (M)
  const int wc   = wid & 3;            // 0..3 (N)
  const int lr   = lane & 15;
  const int g    = lane >> 4;          // 0..3

  const unsigned short* aSrc = A  + (size_t)by * 256 * K;
  const unsigned short* bSrc = BT + (size_t)bx * 256 * K;

  // staging source offsets (inverse-swizzled global, linear LDS dest)
  int aoff[2], boff[2];
#pragma unroll
  for (int i = 0; i < 2; ++i) {
    const int p   = (i * 512 + t) * 16;
    const int lo  = p ^ (((p >> 7) & 7) << 4);
    const int rih = lo >> 7;
    const int kbe = (lo & 127) >> 1;
    aoff[i] = (((rih >> 6) << 7) + (rih & 63)) * K + kbe;
    boff[i] = (((rih >> 5) << 6) + (rih & 31)) * K + kbe;
  }
  const int ldst = wid << 10;

  auto stageA = [&](int h, int k0, char* bufA) {
#pragma unroll
    for (int i = 0; i < 2; ++i)
      GLOAD16(aSrc + aoff[i] + h * (64 * K) + k0, bufA + h * 16384 + i * 8192 + ldst);
  };
  auto stageB = [&](int h, int k0, char* bufB) {
#pragma unroll
    for (int i = 0; i < 2; ++i)
      GLOAD16(bSrc + boff[i] + h * (32 * K) + k0, bufB + h * 16384 + i * 8192 + ldst);
  };

  // swizzled ds_read addresses
  const int sw   = (lr & 7) << 4;
  const int col0 = (g * 16) ^ sw;
  const int col1 = (64 + g * 16) ^ sw;
  const int aRow = (wr * 64 + lr) * 128;
  const int bRow = (wc * 32 + lr) * 128;

  f32x4_t acc[8][4] = {};
  bf16x8_t av0[4][2], av1[4][2];       // A quadrant frags [m2][ks]
  bf16x8_t bv0[2][2], bv1[2][2];       // B pair frags [e][ks]

#define LDA_INTO(dst, bufA_, q)                                                \
  {                                                                            \
    const char* _b = (bufA_) + (q) * 16384 + aRow;                             \
    _Pragma("unroll") for (int m2 = 0; m2 < 4; ++m2) {                         \
      dst[m2][0] = *(const bf16x8_t*)(_b + m2 * 2048 + col0);                  \
      dst[m2][1] = *(const bf16x8_t*)(_b + m2 * 2048 + col1);                  \
    }                                                                          \
  }
#define LDB_INTO(dst, bufB_, pair)                                             \
  {                                                                            \
    _Pragma("unroll") for (int e = 0; e < 2; ++e) {                            \
      const int nf = (pair) * 2 + e;                                           \
      const char* _b = (bufB_) + (nf >> 1) * 16384 + (nf & 1) * 2048 + bRow;   \
      dst[e][0] = *(const bf16x8_t*)(_b + col0);                               \
      dst[e][1] = *(const bf16x8_t*)(_b + col1);                               \
    }                                                                          \
  }
#define MFMAQ(AV, BV, Q, PAIR)                                                 \
  _Pragma("unroll") for (int m2 = 0; m2 < 4; ++m2)                             \
  _Pragma("unroll") for (int e = 0; e < 2; ++e)                                \
  _Pragma("unroll") for (int ks = 0; ks < 2; ++ks)                             \
    acc[(Q) * 4 + m2][(PAIR) * 2 + e] = __builtin_amdgcn_mfma_f32_16x16x32_bf16( \
        AV[m2][ks], BV[e][ks], acc[(Q) * 4 + m2][(PAIR) * 2 + e], 0, 0, 0);

#define SBR __builtin_amdgcn_sched_barrier(0)
  // barrier -> counted lgkm wait -> fence -> boost
#define TAIL(NN)                                                               \
  SBR; __builtin_amdgcn_s_barrier();                                           \
  asm volatile("s_waitcnt lgkmcnt(" #NN ")" ::: "memory");                     \
  SBR; __builtin_amdgcn_s_setprio(1);
#define PEND                                                                   \
  __builtin_amdgcn_s_setprio(0); SBR; __builtin_amdgcn_s_barrier();

  // ---- prologue: tile0 full + tile1 {A-h0, B-h1}; pre-read av0 AND bv0
  // (reads are after vmcnt(4)->barrier, so all waves' tile0 DMA has landed)
  {
    char* b0A = lds;
    char* b0B = lds + 32768;
    char* b1A = lds + 65536;
    char* b1B = b1A + 32768;
    stageA(0, 0, b0A); stageA(1, 0, b0A);
    stageB(0, 0, b0B); stageB(1, 0, b0B);
    stageA(0, BK, b1A);
    stageB(1, BK, b1B);
    asm volatile("s_waitcnt vmcnt(4)" ::: "memory");  // tile0 landed (own)
    __builtin_amdgcn_s_barrier();                     // -> landed (all waves)
    LDA_INTO(av0, b0A, 0);
    LDB_INTO(bv0, b0B, 0);
    SBR;
  }

  for (int kt = 0; kt < NKT; ++kt) {
    char* cA = lds + (kt & 1) * 65536;
    char* cB = cA + 32768;
    char* nA = lds + ((kt + 1) & 1) * 65536;
    char* nB = nA + 32768;
    const int k1 = (kt + 1) * BK;
    const int k2 = (kt + 2) * BK;
    const bool s1 = kt + 1 < NKT;
    const bool s2 = kt + 2 < NKT;

    // P1: stage (kt+1)Ah1 -> nA; drain av0n+bv0n; M1=(q0,p0);
    //     post-M1: read bv1 <- cB pair1 (covered by P4(kt-1) vmcnt+barrier)
    if (s1) stageA(1, k1, nA);
    TAIL(0);
    MFMAQ(av0, bv0, 0, 0);
    LDB_INTO(bv1, cB, 1);
    PEND;

    // P2: read av1 <- cA q1; stage (kt+1)Bh0 -> nB; drain bv1 keep av1;
    //     M2=(q0,p1)
    LDA_INTO(av1, cA, 1);
    SBR;
    if (s1) stageB(0, k1, nB);
    TAIL(8); MFMAQ(av0, bv1, 0, 1); PEND;

    // P3: stage (kt+2)Ah0 -> cA; drain av1; M3=(q1,p1)
    if (s2) stageA(0, k2, cA);
    TAIL(0); MFMAQ(av1, bv1, 1, 1); PEND;

    // P4: stage (kt+2)Bh1 -> cB; counted vmcnt; read next av0 (keep in
    //     flight); M4=(q1,p0); post-M4: read next bv0 <- nB pair0
    //     (covered by THIS phase's vmcnt(4) -> TAIL barrier)
    if (s2) stageB(1, k2, cB);
    if (s2) { asm volatile("s_waitcnt vmcnt(4)" ::: "memory"); }
    else    { asm volatile("s_waitcnt vmcnt(0)" ::: "memory"); }
    SBR;
    if (s1) {
      LDA_INTO(av0, nA, 0);
      TAIL(8);
    } else {
      TAIL(0);
    }
    MFMAQ(av1, bv0, 1, 0);
    if (s1) { LDB_INTO(bv0, nB, 0); }
    PEND;
  }

  // ---- epilogue: C/D map col=lane&15, row=(lane>>4)*4+j
  const int rbase = by * 256 + wr * 128 + g * 4;
  const int cbase = bx * 256 + wc * 64 + lr;
#pragma unroll
  for (int m = 0; m < 8; ++m) {
#pragma unroll
    for (int nf = 0; nf < 4; ++nf) {
      const int col = cbase + nf * 16;
#pragma unroll
      for (int j = 0; j < 4; ++j) {
        const size_t off = (size_t)(rbase + (m >> 2) * 64 + (m & 3) * 16 + j) * N + col;
        if constexpr (OUT_BF16) {
          Cb[off] = f32_to_bf16_bits(acc[m][nf][j]);
        } else {
          Cf[off] = acc[m][nf][j] + bias[col];
        }
      }
    }
  }
#undef LDA_INTO
#undef LDB_INTO
#undef MFMAQ
#undef SBR
#undef TAIL
#undef PEND
}

// ---------------------------------------------------------------- attention
__global__ __launch_bounds__(256) void attn_heads(
    const unsigned short* __restrict__ qkv,  // [T][6144] bf16
    unsigned short* __restrict__ attn) {     // [T][2048] bf16
  __shared__ __align__(16) unsigned short sQKV[NQKV];
  __shared__ float sW[16][16];

  const int t = threadIdx.x;
  const size_t qbase = (size_t)blockIdx.x * NQKV;

  const uint4* gp = (const uint4*)(qkv + qbase);
  uint4* l = (uint4*)sQKV;
#pragma unroll
  for (int i = 0; i < 3; ++i) {
    const int idx = i * 256 + t;
    int dst = idx;
    if (idx >= 256 && idx < 512) {
      const int r = (idx - 256) >> 4;
      const int c = idx & 15;
      dst = 256 + r * 16 + (c ^ (r & 7));
    }
    l[dst] = gp[idx];
  }
  __syncthreads();

  const int h = t >> 4;
  const int H = t & 15;
  const bf16x8_t* q8 = (const bf16x8_t*)sQKV + h * 16;
  const bf16x8_t* k8 = (const bf16x8_t*)sQKV + 256;
  float s = 0.f;
#pragma unroll
  for (int d8 = 0; d8 < 16; ++d8) {
    bf16x8_t qv = q8[d8];
    bf16x8_t kv = k8[H * 16 + (d8 ^ (H & 7))];
#pragma unroll
    for (int j = 0; j < 8; ++j)
      s = fmaf((float)qv[j], (float)kv[j], s);
  }
  s *= 0.08838834764831843f;

  float mx = s;
#pragma unroll
  for (int o = 8; o; o >>= 1) mx = fmaxf(mx, __shfl_xor(mx, o));
  const float e = __expf(s - mx);
  float sum = e;
#pragma unroll
  for (int o = 8; o; o >>= 1) sum += __shfl_xor(sum, o);
  sW[h][H] = e / sum;
  __syncthreads();

  const int d0c = t & 15;
  const bf16x8_t* v8 = (const bf16x8_t*)sQKV + 512;
  float accv[8] = {};
#pragma unroll
  for (int j = 0; j < 16; ++j) {
    const float w = sW[h][j];
    const bf16x8_t vv = v8[j * 16 + d0c];
#pragma unroll
    for (int jj = 0; jj < 8; ++jj)
      accv[jj] = fmaf(w, (float)vv[jj], accv[jj]);
  }
  bf16x8_t o;
#pragma unroll
  for (int jj = 0; jj < 8; ++jj) o[jj] = (__bf16)accv[jj];
  *(bf16x8_t*)(attn + (size_t)blockIdx.x * EMB + h * 128 + d0c * 8) = o;
}

// ---------------------------------------------------------------- launch
extern "C" void kernel_launch(void* const* d_in, const int* in_sizes, int n_in,
                              void* d_out, int out_size, void* d_ws, size_t ws_size,
                              hipStream_t stream) {
  const float* x    = (const float*)d_in[0];
  const float* Wqkv = (const float*)d_in[1];
  const float* Wout = (const float*)d_in[2];
  const float* bout = (const float*)d_in[3];
  float* out = (float*)d_out;

  unsigned short* xb    = (unsigned short*)d_ws;          // 33,554,432
  unsigned short* wqkvT = xb    + (size_t)33554432;       // 12,582,912
  unsigned short* woutT = wqkvT + (size_t)12582912;       //  4,194,304
  unsigned short* qkv   = woutT + (size_t)4194304;        // 100,663,296
  unsigned short* attn  = qkv   + (size_t)100663296;      // 33,554,432

  cvt_f32_bf16<<<2048, 256, 0, stream>>>((const float4*)x, (ushort4*)xb, 33554432 / 4);
  transpose_cvt<<<dim3(6144 / 32, 2048 / 32), dim3(32, 8), 0, stream>>>(Wqkv, wqkvT, 2048, 6144);
  transpose_cvt<<<dim3(2048 / 32, 2048 / 32), dim3(32, 8), 0, stream>>>(Wout, woutT, 2048, 2048);
  // qkv = x @ W_qkv : grid 64*24 = 1536 (%8==0)
  gemm_bt<true><<<(16384 / 256) * (6144 / 256), 512, 0, stream>>>(
      xb, wqkvT, qkv, nullptr, nullptr, 16384, 6144);
  attn_heads<<<TOKENS, 256, 0, stream>>>(qkv, attn);
  // out = attn @ W_out + b_out : grid 64*8 = 512 (%8==0)
  gemm_bt<false><<<(16384 / 256) * (2048 / 256), 512, 0, stream>>>(
      attn, woutT, nullptr, out, bout, 16384, 2048);
}

// Round 9
// 627.814 us; speedup vs baseline: 1.8812x; 1.0258x over previous
//
#include <hip/hip_runtime.h>
#include <hip/hip_bf16.h>
#include <cstdint>

// B=4, S=4096, E=2048, H=16, D=128 -> 16384 independent tokens.
// qkv = x @ W_qkv (16384x2048x6144); per-token 16x16 head mix;
// out = attn @ W_out + b_out (16384x2048x2048).

#define TOKENS 16384
#define EMB    2048
#define NQKV   6144

typedef __bf16 bf16x8_t __attribute__((ext_vector_type(8)));
typedef float  f32x4_t  __attribute__((ext_vector_type(4)));

#define GLOAD16(gsrc, ldst)                                                    \
  __builtin_amdgcn_global_load_lds(                                            \
      (const __attribute__((address_space(1))) void*)(uintptr_t)(gsrc),        \
      (__attribute__((address_space(3))) void*)(uint32_t)(uintptr_t)(ldst),    \
      16, 0, 0)

static __device__ __forceinline__ unsigned short f32_to_bf16_bits(float f) {
  union { float f; uint32_t u; } x; x.f = f;
  uint32_t u = x.u;
  u += 0x7fffu + ((u >> 16) & 1u);   // round-to-nearest-even
  return (unsigned short)(u >> 16);
}

// ---------------------------------------------------------------- converts
__global__ __launch_bounds__(256) void cvt_f32_bf16(
    const float4* __restrict__ in, ushort4* __restrict__ out, int n4) {
  const int stride = gridDim.x * blockDim.x;
  for (int i = blockIdx.x * blockDim.x + threadIdx.x; i < n4; i += stride) {
    float4 v = in[i];
    ushort4 o;
    o.x = f32_to_bf16_bits(v.x);
    o.y = f32_to_bf16_bits(v.y);
    o.z = f32_to_bf16_bits(v.z);
    o.w = f32_to_bf16_bits(v.w);
    out[i] = o;
  }
}

// transpose R x C f32 -> C x R bf16
__global__ __launch_bounds__(256) void transpose_cvt(
    const float* __restrict__ in, unsigned short* __restrict__ out, int R, int C) {
  __shared__ float tile[32][33];
  const int bx = blockIdx.x * 32;
  const int by = blockIdx.y * 32;
  const int tx = threadIdx.x;
  const int ty = threadIdx.y;
#pragma unroll
  for (int j = 0; j < 32; j += 8)
    tile[ty + j][tx] = in[(size_t)(by + ty + j) * C + bx + tx];
  __syncthreads();
#pragma unroll
  for (int j = 0; j < 32; j += 8)
    out[(size_t)(bx + ty + j) * R + by + tx] = f32_to_bf16_bits(tile[tx][ty + j]);
}

// ---------------------------------------------------------------- GEMM
// 256x256 tile, BK=64, 8 waves (2M x 4N), 4 phases/K-tile.
// Full-window schedule: every MFMA cluster runs while the NEXT cluster's
// ds_reads execute on the DS pipe. Stages (all for kt+2): P2 A-h0, P3 B-h0,
// P4 A-h1+B-h1. vmcnt(6)@P3 / vmcnt(4)@P4 placed BEFORE the phase's stages.
// Reads: bv1@P1-head, av1 post-M1, av0n@P4 post-vmcnt, bv0n post-M4.
// Counted lgkm drains: P1(4), P2(8), P3(0), P4(8). All reads formally
// covered by (all-waves vmcnt -> barrier); all DMA overwrites issue after a
// barrier following their readers' drains. FIFO-sim verified.
template <bool OUT_BF16>
__global__ __launch_bounds__(512, 1) void gemm_bt(
    const unsigned short* __restrict__ A,
    const unsigned short* __restrict__ BT,
    unsigned short* __restrict__ Cb,
    float* __restrict__ Cf,
    const float* __restrict__ bias,
    int M, int N) {
  constexpr int K = 2048;
  constexpr int BK = 64;
  constexpr int NKT = K / BK;          // 32
  __shared__ __align__(16) char lds[131072];  // [2 bufs][A 32KB | B 32KB]

  const int nbx = N / 256;
  const int nwg = gridDim.x;           // % 8 == 0
  const int bid = blockIdx.x;
  const int swzb = (bid & 7) * (nwg >> 3) + (bid >> 3);
  const int by = swzb / nbx;
  const int bx = swzb % nbx;

  const int t    = threadIdx.x;
  const int lane = t & 63;
  const int wid  = t >> 6;             // 0..7
  const int wr   = wid >> 2;           // 0..1 (M)
  const int wc   = wid & 3;            // 0..3 (N)
  const int lr   = lane & 15;
  const int g    = lane >> 4;          // 0..3

  const unsigned short* aSrc = A  + (size_t)by * 256 * K;
  const unsigned short* bSrc = BT + (size_t)bx * 256 * K;

  // staging source offsets (inverse-swizzled global, linear LDS dest)
  int aoff[2], boff[2];
#pragma unroll
  for (int i = 0; i < 2; ++i) {
    const int p   = (i * 512 + t) * 16;
    const int lo  = p ^ (((p >> 7) & 7) << 4);
    const int rih = lo >> 7;
    const int kbe = (lo & 127) >> 1;
    aoff[i] = (((rih >> 6) << 7) + (rih & 63)) * K + kbe;
    boff[i] = (((rih >> 5) << 6) + (rih & 31)) * K + kbe;
  }
  const int ldst = wid << 10;

  auto stageA = [&](int h, int k0, char* bufA) {
#pragma unroll
    for (int i = 0; i < 2; ++i)
      GLOAD16(aSrc + aoff[i] + h * (64 * K) + k0, bufA + h * 16384 + i * 8192 + ldst);
  };
  auto stageB = [&](int h, int k0, char* bufB) {
#pragma unroll
    for (int i = 0; i < 2; ++i)
      GLOAD16(bSrc + boff[i] + h * (32 * K) + k0, bufB + h * 16384 + i * 8192 + ldst);
  };

  // swizzled ds_read addresses
  const int sw   = (lr & 7) << 4;
  const int col0 = (g * 16) ^ sw;
  const int col1 = (64 + g * 16) ^ sw;
  const int aRow = (wr * 64 + lr) * 128;
  const int bRow = (wc * 32 + lr) * 128;

  f32x4_t acc[8][4] = {};
  bf16x8_t av0[4][2], av1[4][2];       // A quadrant frags [m2][ks]
  bf16x8_t bv0[2][2], bv1[2][2];       // B pair frags [e][ks]

#define LDA_INTO(dst, bufA_, q)                                                \
  {                                                                            \
    const char* _b = (bufA_) + (q) * 16384 + aRow;                             \
    _Pragma("unroll") for (int m2 = 0; m2 < 4; ++m2) {                         \
      dst[m2][0] = *(const bf16x8_t*)(_b + m2 * 2048 + col0);                  \
      dst[m2][1] = *(const bf16x8_t*)(_b + m2 * 2048 + col1);                  \
    }                                                                          \
  }
#define LDB_INTO(dst, bufB_, pair)                                             \
  {                                                                            \
    _Pragma("unroll") for (int e = 0; e < 2; ++e) {                            \
      const int nf = (pair) * 2 + e;                                           \
      const char* _b = (bufB_) + (nf >> 1) * 16384 + (nf & 1) * 2048 + bRow;   \
      dst[e][0] = *(const bf16x8_t*)(_b + col0);                               \
      dst[e][1] = *(const bf16x8_t*)(_b + col1);                               \
    }                                                                          \
  }
#define MFMAQ(AV, BV, Q, PAIR)                                                 \
  _Pragma("unroll") for (int m2 = 0; m2 < 4; ++m2)                             \
  _Pragma("unroll") for (int e = 0; e < 2; ++e)                                \
  _Pragma("unroll") for (int ks = 0; ks < 2; ++ks)                             \
    acc[(Q) * 4 + m2][(PAIR) * 2 + e] = __builtin_amdgcn_mfma_f32_16x16x32_bf16( \
        AV[m2][ks], BV[e][ks], acc[(Q) * 4 + m2][(PAIR) * 2 + e], 0, 0, 0);

#define SBR __builtin_amdgcn_sched_barrier(0)
  // barrier -> counted lgkm wait -> fence -> boost
#define TAIL(NN)                                                               \
  SBR; __builtin_amdgcn_s_barrier();                                           \
  asm volatile("s_waitcnt lgkmcnt(" #NN ")" ::: "memory");                     \
  SBR; __builtin_amdgcn_s_setprio(1);
#define PEND                                                                   \
  __builtin_amdgcn_s_setprio(0); SBR; __builtin_amdgcn_s_barrier();
#define VMC(NN) asm volatile("s_waitcnt vmcnt(" #NN ")" ::: "memory"); SBR;

  // One K-tile. VM3/VM4 = vmcnt tokens at P3/P4; T4 = P4 lgkm TAIL count.
  // Steady: (6,4,8). Tile NKT-2: (4,0,8). Tile NKT-1: (0,0,0).
#define BODY(KT, S1, S2, VM3, VM4, T4)                                         \
  {                                                                            \
    char* cA = lds + ((KT) & 1) * 65536;                                       \
    char* cB = cA + 32768;                                                     \
    char* nA = lds + (((KT) + 1) & 1) * 65536;                                 \
    char* nB = nA + 32768;                                                     \
    const int k2 = ((KT) + 2) * BK;                                            \
    /* P1: head read bv1(kt) (covered: vmcnt@P4(kt-1)+barrier); TAIL(4)        \
       drains av0,bv0 (read at P4(kt-1)); M1=(av0,bv0); post: read av1(kt) */  \
    LDB_INTO(bv1, cB, 1); SBR;                                                 \
    TAIL(4);                                                                   \
    MFMAQ(av0, bv0, 0, 0);                                                     \
    LDA_INTO(av1, cA, 1);                                                      \
    PEND;                                                                      \
    /* P2: stage A-h0(kt+2)->cA (readers drained P1); TAIL(8) drains bv1,      \
       keeps av1 in flight under M2; M2=(av0,bv1) */                           \
    if (S2) { stageA(0, k2, cA); } SBR;                                        \
    TAIL(8);                                                                   \
    MFMAQ(av0, bv1, 0, 1);                                                     \
    PEND;                                                                      \
    /* P3: vmcnt(VM3) [drains A-h0/B-h0(kt+1)]; stage B-h0(kt+2)->cB;          \
       TAIL(0) drains av1; M3=(av1,bv1) */                                     \
    VMC(VM3);                                                                  \
    if (S2) { stageB(0, k2, cB); } SBR;                                        \
    TAIL(0);                                                                   \
    MFMAQ(av1, bv1, 1, 1);                                                     \
    PEND;                                                                      \
    /* P4: vmcnt(VM4) [drains A-h1/B-h1(kt+1)]; stage A-h1+B-h1(kt+2);         \
       read av0n (covered: vmcnt@P3+barrier); TAIL(T4) keeps av0n;             \
       M4=(av1,bv0); post: read bv0n (covered same) */                         \
    VMC(VM4);                                                                  \
    if (S2) { stageA(1, k2, cA); stageB(1, k2, cB); } SBR;                     \
    if (S1) { LDA_INTO(av0, nA, 0); } SBR;                                     \
    TAIL(T4);                                                                  \
    MFMAQ(av1, bv0, 1, 0);                                                     \
    if (S1) { LDB_INTO(bv0, nB, 0); }                                          \
    PEND;                                                                      \
  }

  // ---- prologue: stage tile0 (8 loads) then tile1 in steady FIFO order
  // [a0,b0,a1,b1]; vmcnt(8) = tile0 landed; barrier; pre-read av0,bv0(t0).
  {
    char* b0A = lds;
    char* b0B = lds + 32768;
    char* b1A = lds + 65536;
    char* b1B = b1A + 32768;
    stageA(0, 0, b0A); stageA(1, 0, b0A);
    stageB(0, 0, b0B); stageB(1, 0, b0B);
    stageA(0, BK, b1A);
    stageB(0, BK, b1B);
    stageA(1, BK, b1A);
    stageB(1, BK, b1B);
    asm volatile("s_waitcnt vmcnt(8)" ::: "memory");  // tile0 landed
    __builtin_amdgcn_s_barrier();
    LDA_INTO(av0, b0A, 0);
    LDB_INTO(bv0, b0B, 0);
    SBR;
  }

  for (int kt = 0; kt < NKT - 2; ++kt) {
    BODY(kt, 1, 1, 6, 4, 8);
  }
  BODY(NKT - 2, 1, 0, 4, 0, 8);
  BODY(NKT - 1, 0, 0, 0, 0, 0);

  // ---- epilogue: C/D map col=lane&15, row=(lane>>4)*4+j
  const int rbase = by * 256 + wr * 128 + g * 4;
  const int cbase = bx * 256 + wc * 64 + lr;
#pragma unroll
  for (int m = 0; m < 8; ++m) {
#pragma unroll
    for (int nf = 0; nf < 4; ++nf) {
      const int col = cbase + nf * 16;
#pragma unroll
      for (int j = 0; j < 4; ++j) {
        const size_t off = (size_t)(rbase + (m >> 2) * 64 + (m & 3) * 16 + j) * N + col;
        if constexpr (OUT_BF16) {
          Cb[off] = f32_to_bf16_bits(acc[m][nf][j]);
        } else {
          Cf[off] = acc[m][nf][j] + bias[col];
        }
      }
    }
  }
#undef LDA_INTO
#undef LDB_INTO
#undef MFMAQ
#undef SBR
#undef TAIL
#undef PEND
#undef VMC
#undef BODY
}

// ---------------------------------------------------------------- attention
__global__ __launch_bounds__(256) void attn_heads(
    const unsigned short* __restrict__ qkv,  // [T][6144] bf16
    unsigned short* __restrict__ attn) {     // [T][2048] bf16
  __shared__ __align__(16) unsigned short sQKV[NQKV];
  __shared__ float sW[16][16];

  const int t = threadIdx.x;
  const size_t qbase = (size_t)blockIdx.x * NQKV;

  const uint4* gp = (const uint4*)(qkv + qbase);
  uint4* l = (uint4*)sQKV;
#pragma unroll
  for (int i = 0; i < 3; ++i) {
    const int idx = i * 256 + t;
    int dst = idx;
    if (idx >= 256 && idx < 512) {
      const int r = (idx - 256) >> 4;
      const int c = idx & 15;
      dst = 256 + r * 16 + (c ^ (r & 7));
    }
    l[dst] = gp[idx];
  }
  __syncthreads();

  const int h = t >> 4;
  const int H = t & 15;
  const bf16x8_t* q8 = (const bf16x8_t*)sQKV + h * 16;
  const bf16x8_t* k8 = (const bf16x8_t*)sQKV + 256;
  float s = 0.f;
#pragma unroll
  for (int d8 = 0; d8 < 16; ++d8) {
    bf16x8_t qv = q8[d8];
    bf16x8_t kv = k8[H * 16 + (d8 ^ (H & 7))];
#pragma unroll
    for (int j = 0; j < 8; ++j)
      s = fmaf((float)qv[j], (float)kv[j], s);
  }
  s *= 0.08838834764831843f;

  float mx = s;
#pragma unroll
  for (int o = 8; o; o >>= 1) mx = fmaxf(mx, __shfl_xor(mx, o));
  const float e = __expf(s - mx);
  float sum = e;
#pragma unroll
  for (int o = 8; o; o >>= 1) sum += __shfl_xor(sum, o);
  sW[h][H] = e / sum;
  __syncthreads();

  const int d0c = t & 15;
  const bf16x8_t* v8 = (const bf16x8_t*)sQKV + 512;
  float accv[8] = {};
#pragma unroll
  for (int j = 0; j < 16; ++j) {
    const float w = sW[h][j];
    const bf16x8_t vv = v8[j * 16 + d0c];
#pragma unroll
    for (int jj = 0; jj < 8; ++jj)
      accv[jj] = fmaf(w, (float)vv[jj], accv[jj]);
  }
  bf16x8_t o;
#pragma unroll
  for (int jj = 0; jj < 8; ++jj) o[jj] = (__bf16)accv[jj];
  *(bf16x8_t*)(attn + (size_t)blockIdx.x * EMB + h * 128 + d0c * 8) = o;
}

// ---------------------------------------------------------------- launch
extern "C" void kernel_launch(void* const* d_in, const int* in_sizes, int n_in,
                              void* d_out, int out_size, void* d_ws, size_t ws_size,
                              hipStream_t stream) {
  const float* x    = (const float*)d_in[0];
  const float* Wqkv = (const float*)d_in[1];
  const float* Wout = (const float*)d_in[2];
  const float* bout = (const float*)d_in[3];
  float* out = (float*)d_out;

  unsigned short* xb    = (unsigned short*)d_ws;          // 33,554,432
  unsigned short* wqkvT = xb    + (size_t)33554432;       // 12,582,912
  unsigned short* woutT = wqkvT + (size_t)12582912;       //  4,194,304
  unsigned short* qkv   = woutT + (size_t)4194304;        // 100,663,296
  unsigned short* attn  = qkv   + (size_t)100663296;      // 33,554,432

  cvt_f32_bf16<<<2048, 256, 0, stream>>>((const float4*)x, (ushort4*)xb, 33554432 / 4);
  transpose_cvt<<<dim3(6144 / 32, 2048 / 32), dim3(32, 8), 0, stream>>>(Wqkv, wqkvT, 2048, 6144);
  transpose_cvt<<<dim3(2048 / 32, 2048 / 32), dim3(32, 8), 0, stream>>>(Wout, woutT, 2048, 2048);
  // qkv = x @ W_qkv : grid 64*24 = 1536 (%8==0)
  gemm_bt<true><<<(16384 / 256) * (6144 / 256), 512, 0, stream>>>(
      xb, wqkvT, qkv, nullptr, nullptr, 16384, 6144);
  attn_heads<<<TOKENS, 256, 0, stream>>>(qkv, attn);
  // out = attn @ W_out + b_out : grid 64*8 = 512 (%8==0)
  gemm_bt<false><<<(16384 / 256) * (2048 / 256), 512, 0, stream>>>(
      attn, woutT, nullptr, out, bout, 16384, 2048);
}

// Round 10
// 616.500 us; speedup vs baseline: 1.9157x; 1.0184x over previous
//
#include <hip/hip_runtime.h>
#include <hip/hip_bf16.h>
#include <cstdint>

// B=4, S=4096, E=2048, H=16, D=128 -> 16384 independent tokens.
// qkv = x @ W_qkv (16384x2048x6144); per-token 16x16 head mix;
// out = attn @ W_out + b_out (16384x2048x2048).

#define TOKENS 16384
#define EMB    2048
#define NQKV   6144

typedef __bf16 bf16x8_t __attribute__((ext_vector_type(8)));
typedef float  f32x4_t  __attribute__((ext_vector_type(4)));

#define GLOAD16(gsrc, ldst)                                                    \
  __builtin_amdgcn_global_load_lds(                                            \
      (const __attribute__((address_space(1))) void*)(uintptr_t)(gsrc),        \
      (__attribute__((address_space(3))) void*)(uint32_t)(uintptr_t)(ldst),    \
      16, 0, 0)

static __device__ __forceinline__ unsigned short f32_to_bf16_bits(float f) {
  union { float f; uint32_t u; } x; x.f = f;
  uint32_t u = x.u;
  u += 0x7fffu + ((u >> 16) & 1u);   // round-to-nearest-even
  return (unsigned short)(u >> 16);
}

// ---------------------------------------------------------------- converts
__global__ __launch_bounds__(256) void cvt_f32_bf16(
    const float4* __restrict__ in, ushort4* __restrict__ out, int n4) {
  const int stride = gridDim.x * blockDim.x;
  for (int i = blockIdx.x * blockDim.x + threadIdx.x; i < n4; i += stride) {
    float4 v = in[i];
    ushort4 o;
    o.x = f32_to_bf16_bits(v.x);
    o.y = f32_to_bf16_bits(v.y);
    o.z = f32_to_bf16_bits(v.z);
    o.w = f32_to_bf16_bits(v.w);
    out[i] = o;
  }
}

// transpose R x C f32 -> C x R bf16
__global__ __launch_bounds__(256) void transpose_cvt(
    const float* __restrict__ in, unsigned short* __restrict__ out, int R, int C) {
  __shared__ float tile[32][33];
  const int bx = blockIdx.x * 32;
  const int by = blockIdx.y * 32;
  const int tx = threadIdx.x;
  const int ty = threadIdx.y;
#pragma unroll
  for (int j = 0; j < 32; j += 8)
    tile[ty + j][tx] = in[(size_t)(by + ty + j) * C + bx + tx];
  __syncthreads();
#pragma unroll
  for (int j = 0; j < 32; j += 8)
    out[(size_t)(bx + ty + j) * R + by + tx] = f32_to_bf16_bits(tile[tx][ty + j]);
}

// ---------------------------------------------------------------- GEMM
// 256x256 tile, BK=64, 8 waves (2M x 4N), TWO phases / 2 barriers per K-tile
// (R9 proved read-scheduling is not the limiter; the residual is barrier
// convoys -- 8/K-tile before, 2 now).
//   PhA: read ALL 24 frag b128s + stage Ah1(kt+1); lgkmcnt(0); 32 MFMA
//        (q0p0,q0p1); barrier.
//   PhB: stage B(kt+2)+Ah0(kt+2) into CURRENT bufs (readers drained at PhA
//        lgkm, PhA barrier separates -> formally WAR-safe); 32 MFMA
//        (q1p1,q1p0); vmcnt(6); barrier.
// One vmcnt(6)/K-tile (load-FIFO verified: leaves exactly PhB's 6 loads;
// covers next tile's reads via the trailing barrier).
template <bool OUT_BF16>
__global__ __launch_bounds__(512, 1) void gemm_bt(
    const unsigned short* __restrict__ A,
    const unsigned short* __restrict__ BT,
    unsigned short* __restrict__ Cb,
    float* __restrict__ Cf,
    const float* __restrict__ bias,
    int M, int N) {
  constexpr int K = 2048;
  constexpr int BK = 64;
  constexpr int NKT = K / BK;          // 32
  __shared__ __align__(16) char lds[131072];  // [2 bufs][A 32KB | B 32KB]

  const int nbx = N / 256;
  const int nwg = gridDim.x;           // % 8 == 0
  const int bid = blockIdx.x;
  const int swzb = (bid & 7) * (nwg >> 3) + (bid >> 3);
  const int by = swzb / nbx;
  const int bx = swzb % nbx;

  const int t    = threadIdx.x;
  const int lane = t & 63;
  const int wid  = t >> 6;             // 0..7
  const int wr   = wid >> 2;           // 0..1 (M)
  const int wc   = wid & 3;            // 0..3 (N)
  const int lr   = lane & 15;
  const int g    = lane >> 4;          // 0..3

  const unsigned short* aSrc = A  + (size_t)by * 256 * K;
  const unsigned short* bSrc = BT + (size_t)bx * 256 * K;

  // staging source offsets (inverse-swizzled global, linear LDS dest)
  int aoff[2], boff[2];
#pragma unroll
  for (int i = 0; i < 2; ++i) {
    const int p   = (i * 512 + t) * 16;
    const int lo  = p ^ (((p >> 7) & 7) << 4);
    const int rih = lo >> 7;
    const int kbe = (lo & 127) >> 1;
    aoff[i] = (((rih >> 6) << 7) + (rih & 63)) * K + kbe;
    boff[i] = (((rih >> 5) << 6) + (rih & 31)) * K + kbe;
  }
  const int ldst = wid << 10;

  auto stageA = [&](int h, int k0, char* bufA) {
#pragma unroll
    for (int i = 0; i < 2; ++i)
      GLOAD16(aSrc + aoff[i] + h * (64 * K) + k0, bufA + h * 16384 + i * 8192 + ldst);
  };
  auto stageB = [&](int h, int k0, char* bufB) {
#pragma unroll
    for (int i = 0; i < 2; ++i)
      GLOAD16(bSrc + boff[i] + h * (32 * K) + k0, bufB + h * 16384 + i * 8192 + ldst);
  };

  // swizzled ds_read addresses
  const int sw   = (lr & 7) << 4;
  const int col0 = (g * 16) ^ sw;
  const int col1 = (64 + g * 16) ^ sw;
  const int aRow = (wr * 64 + lr) * 128;
  const int bRow = (wc * 32 + lr) * 128;

  f32x4_t acc[8][4] = {};
  bf16x8_t av0[4][2], av1[4][2];       // A quadrant frags [m2][ks]
  bf16x8_t bv0[2][2], bv1[2][2];       // B pair frags [e][ks]

#define LDA_INTO(dst, bufA_, q)                                                \
  {                                                                            \
    const char* _b = (bufA_) + (q) * 16384 + aRow;                             \
    _Pragma("unroll") for (int m2 = 0; m2 < 4; ++m2) {                         \
      dst[m2][0] = *(const bf16x8_t*)(_b + m2 * 2048 + col0);                  \
      dst[m2][1] = *(const bf16x8_t*)(_b + m2 * 2048 + col1);                  \
    }                                                                          \
  }
#define LDB_INTO(dst, bufB_, pair)                                             \
  {                                                                            \
    _Pragma("unroll") for (int e = 0; e < 2; ++e) {                            \
      const int nf = (pair) * 2 + e;                                           \
      const char* _b = (bufB_) + (nf >> 1) * 16384 + (nf & 1) * 2048 + bRow;   \
      dst[e][0] = *(const bf16x8_t*)(_b + col0);                               \
      dst[e][1] = *(const bf16x8_t*)(_b + col1);                               \
    }                                                                          \
  }
#define MFMAQ(AV, BV, Q, PAIR)                                                 \
  _Pragma("unroll") for (int m2 = 0; m2 < 4; ++m2)                             \
  _Pragma("unroll") for (int e = 0; e < 2; ++e)                                \
  _Pragma("unroll") for (int ks = 0; ks < 2; ++ks)                             \
    acc[(Q) * 4 + m2][(PAIR) * 2 + e] = __builtin_amdgcn_mfma_f32_16x16x32_bf16( \
        AV[m2][ks], BV[e][ks], acc[(Q) * 4 + m2][(PAIR) * 2 + e], 0, 0, 0);

#define SBR __builtin_amdgcn_sched_barrier(0)

  // One K-tile: 2 phases, 2 barriers, 1 lgkm drain, 1 counted vmcnt.
#define BODY(KT, S1, S2, VMN)                                                  \
  {                                                                            \
    char* cA = lds + ((KT) & 1) * 65536;                                       \
    char* cB = cA + 32768;                                                     \
    char* nA = lds + (((KT) + 1) & 1) * 65536;                                 \
    const int k1 = ((KT) + 1) * BK, k2 = ((KT) + 2) * BK;                      \
    /* PhA: all reads (covered by prev PhB vmcnt->barrier); stage Ah1(kt+1)    \
       (nA-q1 readers drained 2 barriers back); drain; MFMA q0 */              \
    LDA_INTO(av0, cA, 0);                                                      \
    LDB_INTO(bv0, cB, 0);                                                      \
    LDB_INTO(bv1, cB, 1);                                                      \
    LDA_INTO(av1, cA, 1); SBR;                                                 \
    if (S1) { stageA(1, k1, nA); } SBR;                                        \
    asm volatile("s_waitcnt lgkmcnt(0)" ::: "memory"); SBR;                    \
    __builtin_amdgcn_s_setprio(1);                                             \
    MFMAQ(av0, bv0, 0, 0);                                                     \
    MFMAQ(av0, bv1, 0, 1);                                                     \
    __builtin_amdgcn_s_setprio(0); SBR;                                        \
    __builtin_amdgcn_s_barrier();                                              \
    /* PhB: stage (kt+2) into CURRENT bufs (readers drained at PhA lgkm,       \
       PhA barrier separates -> WAR-safe); MFMA q1; counted vmcnt; barrier */  \
    if (S2) { stageB(0, k2, cB); stageB(1, k2, cB); stageA(0, k2, cA); } SBR;  \
    __builtin_amdgcn_s_setprio(1);                                             \
    MFMAQ(av1, bv1, 1, 1);                                                     \
    MFMAQ(av1, bv0, 1, 0);                                                     \
    __builtin_amdgcn_s_setprio(0); SBR;                                        \
    asm volatile("s_waitcnt vmcnt(" #VMN ")" ::: "memory"); SBR;               \
    __builtin_amdgcn_s_barrier();                                              \
  }

  // ---- prologue: tile0 (8 loads) + B(1),Ah0(1) (6 loads, the PhB(-1) role);
  // vmcnt(6) = tile0 landed; barrier -> PhA(0) reads formally covered.
  {
    char* b0A = lds;
    char* b0B = lds + 32768;
    char* b1A = lds + 65536;
    char* b1B = b1A + 32768;
    stageA(0, 0, b0A); stageA(1, 0, b0A);
    stageB(0, 0, b0B); stageB(1, 0, b0B);
    stageB(0, BK, b1B); stageB(1, BK, b1B);
    stageA(0, BK, b1A);
    asm volatile("s_waitcnt vmcnt(6)" ::: "memory");
    __builtin_amdgcn_s_barrier();
  }

  for (int kt = 0; kt < NKT - 2; ++kt) {
    BODY(kt, 1, 1, 6);
  }
  BODY(NKT - 2, 1, 0, 0);
  BODY(NKT - 1, 0, 0, 0);

  // ---- epilogue: C/D map col=lane&15, row=(lane>>4)*4+j
  const int rbase = by * 256 + wr * 128 + g * 4;
  const int cbase = bx * 256 + wc * 64 + lr;
#pragma unroll
  for (int m = 0; m < 8; ++m) {
#pragma unroll
    for (int nf = 0; nf < 4; ++nf) {
      const int col = cbase + nf * 16;
#pragma unroll
      for (int j = 0; j < 4; ++j) {
        const size_t off = (size_t)(rbase + (m >> 2) * 64 + (m & 3) * 16 + j) * N + col;
        if constexpr (OUT_BF16) {
          Cb[off] = f32_to_bf16_bits(acc[m][nf][j]);
        } else {
          Cf[off] = acc[m][nf][j] + bias[col];
        }
      }
    }
  }
#undef LDA_INTO
#undef LDB_INTO
#undef MFMAQ
#undef SBR
#undef BODY
}

// ---------------------------------------------------------------- attention
__global__ __launch_bounds__(256) void attn_heads(
    const unsigned short* __restrict__ qkv,  // [T][6144] bf16
    unsigned short* __restrict__ attn) {     // [T][2048] bf16
  __shared__ __align__(16) unsigned short sQKV[NQKV];
  __shared__ float sW[16][16];

  const int t = threadIdx.x;
  const size_t qbase = (size_t)blockIdx.x * NQKV;

  const uint4* gp = (const uint4*)(qkv + qbase);
  uint4* l = (uint4*)sQKV;
#pragma unroll
  for (int i = 0; i < 3; ++i) {
    const int idx = i * 256 + t;
    int dst = idx;
    if (idx >= 256 && idx < 512) {
      const int r = (idx - 256) >> 4;
      const int c = idx & 15;
      dst = 256 + r * 16 + (c ^ (r & 7));
    }
    l[dst] = gp[idx];
  }
  __syncthreads();

  const int h = t >> 4;
  const int H = t & 15;
  const bf16x8_t* q8 = (const bf16x8_t*)sQKV + h * 16;
  const bf16x8_t* k8 = (const bf16x8_t*)sQKV + 256;
  float s = 0.f;
#pragma unroll
  for (int d8 = 0; d8 < 16; ++d8) {
    bf16x8_t qv = q8[d8];
    bf16x8_t kv = k8[H * 16 + (d8 ^ (H & 7))];
#pragma unroll
    for (int j = 0; j < 8; ++j)
      s = fmaf((float)qv[j], (float)kv[j], s);
  }
  s *= 0.08838834764831843f;

  float mx = s;
#pragma unroll
  for (int o = 8; o; o >>= 1) mx = fmaxf(mx, __shfl_xor(mx, o));
  const float e = __expf(s - mx);
  float sum = e;
#pragma unroll
  for (int o = 8; o; o >>= 1) sum += __shfl_xor(sum, o);
  sW[h][H] = e / sum;
  __syncthreads();

  const int d0c = t & 15;
  const bf16x8_t* v8 = (const bf16x8_t*)sQKV + 512;
  float accv[8] = {};
#pragma unroll
  for (int j = 0; j < 16; ++j) {
    const float w = sW[h][j];
    const bf16x8_t vv = v8[j * 16 + d0c];
#pragma unroll
    for (int jj = 0; jj < 8; ++jj)
      accv[jj] = fmaf(w, (float)vv[jj], accv[jj]);
  }
  bf16x8_t o;
#pragma unroll
  for (int jj = 0; jj < 8; ++jj) o[jj] = (__bf16)accv[jj];
  *(bf16x8_t*)(attn + (size_t)blockIdx.x * EMB + h * 128 + d0c * 8) = o;
}

// ---------------------------------------------------------------- launch
extern "C" void kernel_launch(void* const* d_in, const int* in_sizes, int n_in,
                              void* d_out, int out_size, void* d_ws, size_t ws_size,
                              hipStream_t stream) {
  const float* x    = (const float*)d_in[0];
  const float* Wqkv = (const float*)d_in[1];
  const float* Wout = (const float*)d_in[2];
  const float* bout = (const float*)d_in[3];
  float* out = (float*)d_out;

  unsigned short* xb    = (unsigned short*)d_ws;          // 33,554,432
  unsigned short* wqkvT = xb    + (size_t)33554432;       // 12,582,912
  unsigned short* woutT = wqkvT + (size_t)12582912;       //  4,194,304
  unsigned short* qkv   = woutT + (size_t)4194304;        // 100,663,296
  unsigned short* attn  = qkv   + (size_t)100663296;      // 33,554,432

  cvt_f32_bf16<<<2048, 256, 0, stream>>>((const float4*)x, (ushort4*)xb, 33554432 / 4);
  transpose_cvt<<<dim3(6144 / 32, 2048 / 32), dim3(32, 8), 0, stream>>>(Wqkv, wqkvT, 2048, 6144);
  transpose_cvt<<<dim3(2048 / 32, 2048 / 32), dim3(32, 8), 0, stream>>>(Wout, woutT, 2048, 2048);
  // qkv = x @ W_qkv : grid 64*24 = 1536 (%8==0)
  gemm_bt<true><<<(16384 / 256) * (6144 / 256), 512, 0, stream>>>(
      xb, wqkvT, qkv, nullptr, nullptr, 16384, 6144);
  attn_heads<<<TOKENS, 256, 0, stream>>>(qkv, attn);
  // out = attn @ W_out + b_out : grid 64*8 = 512 (%8==0)
  gemm_bt<false><<<(16384 / 256) * (2048 / 256), 512, 0, stream>>>(
      attn, woutT, nullptr, out, bout, 16384, 2048);
}